// Round 4
// baseline (136.468 us; speedup 1.0000x reference)
//
#include <hip/hip_runtime.h>
#include <math.h>

// WignerDRotation: out = Z(alpha) * J * Z(beta) * J * Z(gamma) * x, block-diagonal
// over irreps [0]*256 + [1]*256 + [2]*128 + [3]*64, DIM=2112, CH=32, N=1024.
// All copies of the same l share one d x d composite matrix M_l per batch row.
//
// Round-4 structure: flat copy-style stream. One f4 output per thread per
// iteration, no barriers in steady state, no register blocking: thread t of
// block (n,half) computes out[512*i+t] = sum_q M[p][q]*in[(r-p+q)*8+ch] with
// p = (r-off)%d. Gather loads are L2-amplified (<=7x, L2 has 34 TB/s), HBM
// traffic stays 1x. Stores are perfectly linear. 2048 fine-grained blocks.

namespace {

typedef float f4 __attribute__((ext_vector_type(4)));

constexpr float SQ3_2 = 0.86602540378443864676f;  // sqrt(3)/2
constexpr float S6    = 0.61237243569579452455f;  // sqrt(6)/4
constexpr float S10   = 0.79056941504209483300f;  // sqrt(10)/4
constexpr float S15   = 0.96824583655185422129f;  // sqrt(15)/4

// J_l: real-SH matrix of the y<->z axis swap (Condon-Shortley phase, rows/cols
// ordered m = -l..l). J = J^T = J^-1.
template<int L> struct JM;
template<> struct JM<1> {
  static constexpr float v[3][3] = {
    { 0.f, -1.f, 0.f},
    {-1.f,  0.f, 0.f},
    { 0.f,  0.f, 1.f}};
};
template<> struct JM<2> {
  static constexpr float v[5][5] = {
    { 0.f, 0.f,  0.f,   -1.f,  0.f},
    { 0.f, 1.f,  0.f,    0.f,  0.f},
    { 0.f, 0.f, -0.5f,   0.f, -SQ3_2},
    {-1.f, 0.f,  0.f,    0.f,  0.f},
    { 0.f, 0.f, -SQ3_2,  0.f,  0.5f}};
};
template<> struct JM<3> {
  static constexpr float v[7][7] = {
    { 0.f, 0.f, 0.f, S10,  0.f,   -S6,  0.f},
    { 0.f, 1.f, 0.f, 0.f,  0.f,    0.f, 0.f},
    { 0.f, 0.f, 0.f, S6,   0.f,    S10, 0.f},
    { S10, 0.f, S6,  0.f,  0.f,    0.f, 0.f},
    { 0.f, 0.f, 0.f, 0.f, -0.25f,  0.f, -S15},
    {-S6,  0.f, S10, 0.f,  0.f,    0.f, 0.f},
    { 0.f, 0.f, 0.f, 0.f, -S15,    0.f, 0.25f}};
};

// Column q of M_l = Zalpha * J * Zbeta * J * Zgamma. Column-local: Z only mixes
// m <-> -m inside a column, so each lane computes one column independently.
template<int L>
__device__ inline void compute_M_col(int q, float al, float be, float ga, float* M) {
  constexpr int D = 2 * L + 1;
  const int mq = q - L;
  float sg, cg;
  sincosf((float)mq * ga, &sg, &cg);
  float v[D];
#pragma unroll
  for (int p = 0; p < D; ++p)
    v[p] = cg * JM<L>::v[p][q] + sg * JM<L>::v[p][(D - 1) - q];
  float c1, s1;
  sincosf(be, &s1, &c1);
  float cb[L + 1], sb[L + 1];
  cb[0] = 1.f; sb[0] = 0.f;
  cb[1] = c1;  sb[1] = s1;
#pragma unroll
  for (int k = 2; k <= L; ++k) {
    cb[k] = 2.f * c1 * cb[k - 1] - cb[k - 2];
    sb[k] = 2.f * c1 * sb[k - 1] - sb[k - 2];
  }
  float w[D];
#pragma unroll
  for (int p = 0; p < D; ++p) {
    const int mp = p - L;
    const int am = mp < 0 ? -mp : mp;
    const float c = cb[am];
    const float s = mp < 0 ? -sb[am] : sb[am];
    w[p] = c * v[p] - s * v[(D - 1) - p];
  }
  float u[D];
#pragma unroll
  for (int p = 0; p < D; ++p) {
    float acc = 0.f;
#pragma unroll
    for (int r = 0; r < D; ++r) acc = fmaf(JM<L>::v[p][r], w[r], acc);
    u[p] = acc;
  }
  sincosf(al, &s1, &c1);
  float ca[L + 1], sa[L + 1];
  ca[0] = 1.f; sa[0] = 0.f;
  ca[1] = c1;  sa[1] = s1;
#pragma unroll
  for (int k = 2; k <= L; ++k) {
    ca[k] = 2.f * c1 * ca[k - 1] - ca[k - 2];
    sa[k] = 2.f * c1 * sa[k - 1] - sa[k - 2];
  }
#pragma unroll
  for (int p = 0; p < D; ++p) {
    const int mp = p - L;
    const int am = mp < 0 ? -mp : mp;
    const float c = ca[am];
    const float s = mp < 0 ? -sa[am] : sa[am];
    M[p * D + q] = c * u[p] - s * u[(D - 1) - p];
  }
}

// ws layout per batch row n (96 floats): M3(7x7)@0..48, M2(5x5)@49..73, M1(3x3)@74..82.
__global__ __launch_bounds__(256) void build_M_kernel(
    const float* __restrict__ alpha, const float* __restrict__ beta,
    const float* __restrict__ gamma, float* __restrict__ ws, int n_batch) {
  const int t = threadIdx.x;
  const int n = blockIdx.x * 16 + (t >> 4);
  const int col = t & 15;
  if (n >= n_batch || col >= 15) return;
  const float al = alpha[n], be = beta[n], ga = gamma[n];
  float* w = ws + (size_t)n * 96;
  if (col < 7)       compute_M_col<3>(col,      al, be, ga, w);
  else if (col < 12) compute_M_col<2>(col - 7,  al, be, ga, w + 49);
  else               compute_M_col<1>(col - 12, al, be, ga, w + 74);
}

// One output element: row r (global), section start `off`, channel quad `ch`.
// p = position of r inside its copy; gathers the copy's d rows from global
// (L2-resident: neighboring lanes/iterations reuse the same lines).
template<int D>
__device__ inline f4 apply_elem(const f4* __restrict__ inN,
                                const float* __restrict__ M,  // LDS, D*D
                                int r, int off, int ch) {
  const int p = (r - off) % D;
  const float* Mrow = M + p * D;
  const f4* b = inN + (r - p) * 8 + ch;
  f4 a = Mrow[0] * b[0];
#pragma unroll
  for (int q = 1; q < D; ++q) a += Mrow[q] * b[q * 8];
  return a;
}

// 2048 blocks: (n = bid>>1, half = bid&1). Half 0: l0 copy + l1 (rows 0..1023);
// half 1: l2 + l3 (rows 1024..2111). Section splits land exactly on the
// 64-row-per-iteration grid (256 = 64*4, 1024 = 64*16, 1664 = 64*26), so every
// unrolled iteration is uniform-l. No barriers after the M preload.
__global__ __launch_bounds__(512) void wigner_stream_kernel(
    const float* __restrict__ in, const float* __restrict__ ws,
    float* __restrict__ out) {
  __shared__ float M[96];
  const int bid = blockIdx.x;
  const int n = bid >> 1;
  const int half = bid & 1;
  const int t = threadIdx.x;
  if (t < 83) M[t] = ws[(size_t)n * 96 + t];
  __syncthreads();

  const size_t base = (size_t)n * 16896;  // 2112*8 f4 per batch row
  const f4* inN = (const f4*)in + base;
  f4* outN = (f4*)out + base;
  const int g = t >> 3;   // row within 64-row slab
  const int ch = t & 7;

  if (half == 0) {
    // l=0: rows 0..255 — identity, pure copy stream.
#pragma unroll
    for (int i = 0; i < 4; ++i) outN[512 * i + t] = inN[512 * i + t];
    // l=1: rows 256..1023
#pragma unroll
    for (int i = 4; i < 16; ++i) {
      const int r = 64 * i + g;
      outN[512 * i + t] = apply_elem<3>(inN, M + 74, r, 256, ch);
    }
  } else {
    // l=2: rows 1024..1663
#pragma unroll
    for (int i = 16; i < 26; ++i) {
      const int r = 64 * i + g;
      outN[512 * i + t] = apply_elem<5>(inN, M + 49, r, 1024, ch);
    }
    // l=3: rows 1664..2111
#pragma unroll
    for (int i = 26; i < 33; ++i) {
      const int r = 64 * i + g;
      outN[512 * i + t] = apply_elem<7>(inN, M, r, 1664, ch);
    }
  }
}

}  // namespace

extern "C" void kernel_launch(void* const* d_in, const int* in_sizes, int n_in,
                              void* d_out, int out_size, void* d_ws, size_t ws_size,
                              hipStream_t stream) {
  const float* in    = (const float*)d_in[0];
  const float* alpha = (const float*)d_in[1];
  const float* beta  = (const float*)d_in[2];
  const float* gamma = (const float*)d_in[3];
  float* out = (float*)d_out;
  const int n_batch = in_sizes[1];  // 1024

  float* ws = (float*)d_ws;
  build_M_kernel<<<(n_batch + 15) / 16, 256, 0, stream>>>(alpha, beta, gamma,
                                                          ws, n_batch);
  wigner_stream_kernel<<<n_batch * 2, 512, 0, stream>>>(in, ws, out);
}

// Round 5
// 113.030 us; speedup vs baseline: 1.2074x; 1.2074x over previous
//
#include <hip/hip_runtime.h>
#include <math.h>

// WignerDRotation: out = Z(alpha) * J * Z(beta) * J * Z(gamma) * x, block-diagonal
// over irreps [0]*256 + [1]*256 + [2]*128 + [3]*64, DIM=2112, CH=32, N=1024.
// All copies of the same l share one d x d composite matrix M_l per batch row.
//
// Round-5 structure: sliding-window grid-stride. Work = 8192 memory-ordered
// units (8 per batch row, copy-aligned). 1023 resident blocks sweep units in
// address order, so concurrently-active addresses form a ~33 MB contiguous
// window sliding over the 554 MB stream (copy-ubench-like DRAM page locality)
// instead of 1024 streams spread across the whole buffer (rounds 1-4).
// Inner compute = round-1's register-blocked per-copy apply (1x amplification).

namespace {

typedef float f4 __attribute__((ext_vector_type(4)));

constexpr float SQ3_2 = 0.86602540378443864676f;  // sqrt(3)/2
constexpr float S6    = 0.61237243569579452455f;  // sqrt(6)/4
constexpr float S10   = 0.79056941504209483300f;  // sqrt(10)/4
constexpr float S15   = 0.96824583655185422129f;  // sqrt(15)/4

// J_l: real-SH matrix of the y<->z axis swap (Condon-Shortley phase, rows/cols
// ordered m = -l..l). J = J^T = J^-1.
template<int L> struct JM;
template<> struct JM<1> {
  static constexpr float v[3][3] = {
    { 0.f, -1.f, 0.f},
    {-1.f,  0.f, 0.f},
    { 0.f,  0.f, 1.f}};
};
template<> struct JM<2> {
  static constexpr float v[5][5] = {
    { 0.f, 0.f,  0.f,   -1.f,  0.f},
    { 0.f, 1.f,  0.f,    0.f,  0.f},
    { 0.f, 0.f, -0.5f,   0.f, -SQ3_2},
    {-1.f, 0.f,  0.f,    0.f,  0.f},
    { 0.f, 0.f, -SQ3_2,  0.f,  0.5f}};
};
template<> struct JM<3> {
  static constexpr float v[7][7] = {
    { 0.f, 0.f, 0.f, S10,  0.f,   -S6,  0.f},
    { 0.f, 1.f, 0.f, 0.f,  0.f,    0.f, 0.f},
    { 0.f, 0.f, 0.f, S6,   0.f,    S10, 0.f},
    { S10, 0.f, S6,  0.f,  0.f,    0.f, 0.f},
    { 0.f, 0.f, 0.f, 0.f, -0.25f,  0.f, -S15},
    {-S6,  0.f, S10, 0.f,  0.f,    0.f, 0.f},
    { 0.f, 0.f, 0.f, 0.f, -S15,    0.f, 0.25f}};
};

// Column q of M_l = Zalpha * J * Zbeta * J * Zgamma. Column-local: Z only mixes
// m <-> -m inside a column, so each lane computes one column independently.
template<int L>
__device__ inline void compute_M_col(int q, float al, float be, float ga, float* M) {
  constexpr int D = 2 * L + 1;
  const int mq = q - L;
  float sg, cg;
  sincosf((float)mq * ga, &sg, &cg);
  float v[D];
#pragma unroll
  for (int p = 0; p < D; ++p)
    v[p] = cg * JM<L>::v[p][q] + sg * JM<L>::v[p][(D - 1) - q];
  float c1, s1;
  sincosf(be, &s1, &c1);
  float cb[L + 1], sb[L + 1];
  cb[0] = 1.f; sb[0] = 0.f;
  cb[1] = c1;  sb[1] = s1;
#pragma unroll
  for (int k = 2; k <= L; ++k) {
    cb[k] = 2.f * c1 * cb[k - 1] - cb[k - 2];
    sb[k] = 2.f * c1 * sb[k - 1] - sb[k - 2];
  }
  float w[D];
#pragma unroll
  for (int p = 0; p < D; ++p) {
    const int mp = p - L;
    const int am = mp < 0 ? -mp : mp;
    const float c = cb[am];
    const float s = mp < 0 ? -sb[am] : sb[am];
    w[p] = c * v[p] - s * v[(D - 1) - p];
  }
  float u[D];
#pragma unroll
  for (int p = 0; p < D; ++p) {
    float acc = 0.f;
#pragma unroll
    for (int r = 0; r < D; ++r) acc = fmaf(JM<L>::v[p][r], w[r], acc);
    u[p] = acc;
  }
  sincosf(al, &s1, &c1);
  float ca[L + 1], sa[L + 1];
  ca[0] = 1.f; sa[0] = 0.f;
  ca[1] = c1;  sa[1] = s1;
#pragma unroll
  for (int k = 2; k <= L; ++k) {
    ca[k] = 2.f * c1 * ca[k - 1] - ca[k - 2];
    sa[k] = 2.f * c1 * sa[k - 1] - sa[k - 2];
  }
#pragma unroll
  for (int p = 0; p < D; ++p) {
    const int mp = p - L;
    const int am = mp < 0 ? -mp : mp;
    const float c = ca[am];
    const float s = mp < 0 ? -sa[am] : sa[am];
    M[p * D + q] = c * u[p] - s * u[(D - 1) - p];
  }
}

// ws layout per batch row n (96 floats): M3(7x7)@0..48, M2(5x5)@49..73, M1(3x3)@74..82.
__global__ __launch_bounds__(256) void build_M_kernel(
    const float* __restrict__ alpha, const float* __restrict__ beta,
    const float* __restrict__ gamma, float* __restrict__ ws, int n_batch) {
  const int t = threadIdx.x;
  const int n = blockIdx.x * 16 + (t >> 4);
  const int col = t & 15;
  if (n >= n_batch || col >= 15) return;
  const float al = alpha[n], be = beta[n], ga = gamma[n];
  float* w = ws + (size_t)n * 96;
  if (col < 7)       compute_M_col<3>(col,      al, be, ga, w);
  else if (col < 12) compute_M_col<2>(col - 7,  al, be, ga, w + 49);
  else               compute_M_col<1>(col - 12, al, be, ga, w + 74);
}

// Register-blocked apply: group g (of 64) owns copy g of the unit (64 copies of
// dim D, contiguous). Lane holds channel-quad ch. 1x read amplification.
template<int D>
__device__ inline void apply_unit(const f4* __restrict__ inU,
                                  f4* __restrict__ outU,
                                  const float* __restrict__ M,  // LDS, D*D
                                  int g, int ch) {
  const f4* src = inU + g * (D * 8) + ch;
  f4* dst = outU + g * (D * 8) + ch;
  f4 v[D];
#pragma unroll
  for (int q = 0; q < D; ++q) v[q] = __builtin_nontemporal_load(src + q * 8);
#pragma unroll
  for (int p = 0; p < D; ++p) {
    const float* Mrow = M + p * D;
    f4 a = Mrow[0] * v[0];
#pragma unroll
    for (int q = 1; q < D; ++q) a += Mrow[q] * v[q];
    __builtin_nontemporal_store(a, dst + p * 8);
  }
}

// Unit table (f4 offsets within one n, 16896 f4 total):
//  k=0   : l0 copy,   [0, 2048)
//  k=1..4: l1, 64 copies x 24 f4, soff = 2048 + (k-1)*1536
//  k=5..6: l2, 64 copies x 40 f4, soff = 8192 + (k-5)*2560
//  k=7   : l3, 64 copies x 56 f4, soff = 13312
// Grid stride 1023 (= 7 mod 8): each block cycles all unit types -> balanced,
// and unit order == memory order -> sliding contiguous window.
__global__ __launch_bounds__(512) void wigner_stream_kernel(
    const float* __restrict__ in, const float* __restrict__ ws,
    float* __restrict__ out, int n_units) {
  __shared__ float M[49];
  const int t = threadIdx.x;
  const int g = t >> 3, ch = t & 7;
  for (int u = blockIdx.x; u < n_units; u += 1023) {
    const int n = u >> 3, k = u & 7;
    const size_t base = (size_t)n * 16896;
    const f4* inN = (const f4*)in + base;
    f4* outN = (f4*)out + base;
    if (k == 0) {
#pragma unroll
      for (int j = 0; j < 4; ++j)
        __builtin_nontemporal_store(
            __builtin_nontemporal_load(inN + t + 512 * j), outN + t + 512 * j);
    } else {
      int D, moff, soff;
      if (k <= 4)      { D = 3; moff = 74; soff = 2048 + (k - 1) * 1536; }
      else if (k <= 6) { D = 5; moff = 49; soff = 8192 + (k - 5) * 2560; }
      else             { D = 7; moff = 0;  soff = 13312; }
      if (t < D * D) M[t] = ws[(size_t)n * 96 + moff + t];
      __syncthreads();
      if (k <= 4)      apply_unit<3>(inN + soff, outN + soff, M, g, ch);
      else if (k <= 6) apply_unit<5>(inN + soff, outN + soff, M, g, ch);
      else             apply_unit<7>(inN + soff, outN + soff, M, g, ch);
      __syncthreads();  // protect LDS M for the next unit
    }
  }
}

}  // namespace

extern "C" void kernel_launch(void* const* d_in, const int* in_sizes, int n_in,
                              void* d_out, int out_size, void* d_ws, size_t ws_size,
                              hipStream_t stream) {
  const float* in    = (const float*)d_in[0];
  const float* alpha = (const float*)d_in[1];
  const float* beta  = (const float*)d_in[2];
  const float* gamma = (const float*)d_in[3];
  float* out = (float*)d_out;
  const int n_batch = in_sizes[1];  // 1024

  float* ws = (float*)d_ws;
  build_M_kernel<<<(n_batch + 15) / 16, 256, 0, stream>>>(alpha, beta, gamma,
                                                          ws, n_batch);
  const int n_units = n_batch * 8;
  const int grid = n_units < 1023 ? n_units : 1023;
  wigner_stream_kernel<<<grid, 512, 0, stream>>>(in, ws, out, n_units);
}

// Round 6
// 108.225 us; speedup vs baseline: 1.2610x; 1.0444x over previous
//
#include <hip/hip_runtime.h>
#include <math.h>

// WignerDRotation: out = Z(alpha) * J * Z(beta) * J * Z(gamma) * x, block-diagonal
// over irreps [0]*256 + [1]*256 + [2]*128 + [3]*64, DIM=2112, CH=32, N=1024.
// All copies of the same l share one d x d composite matrix M_l per batch row.
//
// Round-6 structure: copy-like issue bursts. Each thread handles NC copies per
// unit: cluster of NC*D f4 loads -> FMAs -> cluster of NC*D f4 stores (bursts
// of 8-14 vmem like a deep-unrolled copy, vs 3-7 interleaved before). ZERO
// barriers / ZERO LDS in the stream kernel: M lives in SGPRs (readfirstlane;
// block-uniform, v_fma takes 1 SGPR operand). 1025 all-resident blocks sweep
// 6144 memory-ordered units (sliding contiguous window, from round 5).

namespace {

typedef float f4 __attribute__((ext_vector_type(4)));

constexpr float SQ3_2 = 0.86602540378443864676f;  // sqrt(3)/2
constexpr float S6    = 0.61237243569579452455f;  // sqrt(6)/4
constexpr float S10   = 0.79056941504209483300f;  // sqrt(10)/4
constexpr float S15   = 0.96824583655185422129f;  // sqrt(15)/4

template<int L> struct JM;
template<> struct JM<1> {
  static constexpr float v[3][3] = {
    { 0.f, -1.f, 0.f},
    {-1.f,  0.f, 0.f},
    { 0.f,  0.f, 1.f}};
};
template<> struct JM<2> {
  static constexpr float v[5][5] = {
    { 0.f, 0.f,  0.f,   -1.f,  0.f},
    { 0.f, 1.f,  0.f,    0.f,  0.f},
    { 0.f, 0.f, -0.5f,   0.f, -SQ3_2},
    {-1.f, 0.f,  0.f,    0.f,  0.f},
    { 0.f, 0.f, -SQ3_2,  0.f,  0.5f}};
};
template<> struct JM<3> {
  static constexpr float v[7][7] = {
    { 0.f, 0.f, 0.f, S10,  0.f,   -S6,  0.f},
    { 0.f, 1.f, 0.f, 0.f,  0.f,    0.f, 0.f},
    { 0.f, 0.f, 0.f, S6,   0.f,    S10, 0.f},
    { S10, 0.f, S6,  0.f,  0.f,    0.f, 0.f},
    { 0.f, 0.f, 0.f, 0.f, -0.25f,  0.f, -S15},
    {-S6,  0.f, S10, 0.f,  0.f,    0.f, 0.f},
    { 0.f, 0.f, 0.f, 0.f, -S15,    0.f, 0.25f}};
};

// Column q of M_l = Zalpha * J * Zbeta * J * Zgamma (column-local in q).
template<int L>
__device__ inline void compute_M_col(int q, float al, float be, float ga, float* M) {
  constexpr int D = 2 * L + 1;
  const int mq = q - L;
  float sg, cg;
  sincosf((float)mq * ga, &sg, &cg);
  float v[D];
#pragma unroll
  for (int p = 0; p < D; ++p)
    v[p] = cg * JM<L>::v[p][q] + sg * JM<L>::v[p][(D - 1) - q];
  float c1, s1;
  sincosf(be, &s1, &c1);
  float cb[L + 1], sb[L + 1];
  cb[0] = 1.f; sb[0] = 0.f;
  cb[1] = c1;  sb[1] = s1;
#pragma unroll
  for (int k = 2; k <= L; ++k) {
    cb[k] = 2.f * c1 * cb[k - 1] - cb[k - 2];
    sb[k] = 2.f * c1 * sb[k - 1] - sb[k - 2];
  }
  float w[D];
#pragma unroll
  for (int p = 0; p < D; ++p) {
    const int mp = p - L;
    const int am = mp < 0 ? -mp : mp;
    const float c = cb[am];
    const float s = mp < 0 ? -sb[am] : sb[am];
    w[p] = c * v[p] - s * v[(D - 1) - p];
  }
  float u[D];
#pragma unroll
  for (int p = 0; p < D; ++p) {
    float acc = 0.f;
#pragma unroll
    for (int r = 0; r < D; ++r) acc = fmaf(JM<L>::v[p][r], w[r], acc);
    u[p] = acc;
  }
  sincosf(al, &s1, &c1);
  float ca[L + 1], sa[L + 1];
  ca[0] = 1.f; sa[0] = 0.f;
  ca[1] = c1;  sa[1] = s1;
#pragma unroll
  for (int k = 2; k <= L; ++k) {
    ca[k] = 2.f * c1 * ca[k - 1] - ca[k - 2];
    sa[k] = 2.f * c1 * sa[k - 1] - sa[k - 2];
  }
#pragma unroll
  for (int p = 0; p < D; ++p) {
    const int mp = p - L;
    const int am = mp < 0 ? -mp : mp;
    const float c = ca[am];
    const float s = mp < 0 ? -sa[am] : sa[am];
    M[p * D + q] = c * u[p] - s * u[(D - 1) - p];
  }
}

// ws layout per n (96 floats): M3(7x7)@0..48, M2(5x5)@49..73, M1(3x3)@74..82.
__global__ __launch_bounds__(256) void build_M_kernel(
    const float* __restrict__ alpha, const float* __restrict__ beta,
    const float* __restrict__ gamma, float* __restrict__ ws, int n_batch) {
  const int t = threadIdx.x;
  const int n = blockIdx.x * 16 + (t >> 4);
  const int col = t & 15;
  if (n >= n_batch || col >= 15) return;
  const float al = alpha[n], be = beta[n], ga = gamma[n];
  float* w = ws + (size_t)n * 96;
  if (col < 7)       compute_M_col<3>(col,      al, be, ga, w);
  else if (col < 12) compute_M_col<2>(col - 7,  al, be, ga, w + 49);
  else               compute_M_col<1>(col - 12, al, be, ga, w + 74);
}

// Uniform load forced into SGPR: broadcast L2-hit load + readfirstlane.
__device__ inline float uload(const float* __restrict__ p) {
  return __int_as_float(__builtin_amdgcn_readfirstlane(__float_as_int(*p)));
}

// Group g (of 32) owns NC consecutive copies of dim D. Issue all NC*D loads as
// one burst, all FMAs (M in SGPRs), then all NC*D stores as one burst.
template<int D, int NC>
__device__ inline void apply_unit(const f4* __restrict__ inU,
                                  f4* __restrict__ outU,
                                  const float* __restrict__ Ms,  // SGPR, D*D
                                  int g, int ch) {
  const int base = g * (NC * D * 8) + ch;
  f4 v[NC][D];
#pragma unroll
  for (int j = 0; j < NC; ++j)
#pragma unroll
    for (int q = 0; q < D; ++q)
      v[j][q] = __builtin_nontemporal_load(inU + base + (j * D + q) * 8);
  f4 o[NC][D];
#pragma unroll
  for (int j = 0; j < NC; ++j)
#pragma unroll
    for (int p = 0; p < D; ++p) {
      f4 a = Ms[p * D] * v[j][0];
#pragma unroll
      for (int q = 1; q < D; ++q) a += Ms[p * D + q] * v[j][q];
      o[j][p] = a;
    }
#pragma unroll
  for (int j = 0; j < NC; ++j)
#pragma unroll
    for (int p = 0; p < D; ++p)
      __builtin_nontemporal_store(o[j][p], outU + base + (j * D + p) * 8);
}

template<int D>
__device__ inline void run_unit(const f4* __restrict__ inU, f4* __restrict__ outU,
                                const float* __restrict__ ws_n, int moff,
                                int g, int ch) {
  float Ms[D * D];
#pragma unroll
  for (int i = 0; i < D * D; ++i) Ms[i] = uload(ws_n + moff + i);
  constexpr int NC = (D == 3) ? 4 : 2;
  apply_unit<D, NC>(inU, outU, Ms, g, ch);
}

// Unit table per n (f4 offsets, 16896 f4 per row), 6 units/n, address-ordered:
//  k=0: l0 copy  @0      (2048 f4)        k=1,2: l1 128 copies @2048+3072(k-1)
//  k=3,4: l2 64 copies @8192+2560(k-3)    k=5: l3 64 copies @13312 (3584 f4)
__global__ __launch_bounds__(256) void wigner_stream_kernel(
    const float* __restrict__ in, const float* __restrict__ ws,
    float* __restrict__ out, int n_units, int grid) {
  const int t = threadIdx.x;
  const int g = t >> 3, ch = t & 7;
  for (int u = blockIdx.x; u < n_units; u += grid) {
    const int n = u / 6, k = u - n * 6;
    const size_t base = (size_t)n * 16896;
    const f4* inN = (const f4*)in + base;
    f4* outN = (f4*)out + base;
    const float* ws_n = ws + (size_t)n * 96;
    if (k == 0) {
      f4 c[8];
#pragma unroll
      for (int j = 0; j < 8; ++j)
        c[j] = __builtin_nontemporal_load(inN + t + 256 * j);
#pragma unroll
      for (int j = 0; j < 8; ++j)
        __builtin_nontemporal_store(c[j], outN + t + 256 * j);
    } else if (k <= 2) {
      const int soff = 2048 + (k - 1) * 3072;
      run_unit<3>(inN + soff, outN + soff, ws_n, 74, g, ch);
    } else if (k <= 4) {
      const int soff = 8192 + (k - 3) * 2560;
      run_unit<5>(inN + soff, outN + soff, ws_n, 49, g, ch);
    } else {
      run_unit<7>(inN + 13312, outN + 13312, ws_n, 0, g, ch);
    }
  }
}

}  // namespace

extern "C" void kernel_launch(void* const* d_in, const int* in_sizes, int n_in,
                              void* d_out, int out_size, void* d_ws, size_t ws_size,
                              hipStream_t stream) {
  const float* in    = (const float*)d_in[0];
  const float* alpha = (const float*)d_in[1];
  const float* beta  = (const float*)d_in[2];
  const float* gamma = (const float*)d_in[3];
  float* out = (float*)d_out;
  const int n_batch = in_sizes[1];  // 1024

  float* ws = (float*)d_ws;
  build_M_kernel<<<(n_batch + 15) / 16, 256, 0, stream>>>(alpha, beta, gamma,
                                                          ws, n_batch);
  const int n_units = n_batch * 6;
  const int grid = n_units < 1025 ? n_units : 1025;  // all-resident, ~coprime w/ 6
  wigner_stream_kernel<<<grid, 256, 0, stream>>>(in, ws, out, n_units, grid);
}

// Round 7
// 103.667 us; speedup vs baseline: 1.3164x; 1.0440x over previous
//
#include <hip/hip_runtime.h>
#include <math.h>

// WignerDRotation: out = Z(alpha) * J * Z(beta) * J * Z(gamma) * x, block-diagonal
// over irreps [0]*256 + [1]*256 + [2]*128 + [3]*64, DIM=2112, CH=32, N=1024.
// All copies of the same l share one d x d composite matrix M_l per batch row.
//
// Round-7 structure: SINGLE fused kernel (removes the serial build_M dispatch +
// ws round-trip of rounds 2-6). Per transform unit: <=7 lanes compute the d x d
// composite M into LDS (barrier), all lanes issue the copy-like data burst
// FIRST, then pull M to SGPRs via broadcast ds_read+readfirstlane (latency
// hidden under the HBM burst), FMA, store burst. Keeps round 6's winners:
// burst issue (8-14 vmem clusters), SGPR-operand FMAs, sliding-window
// grid-stride over 6144 memory-ordered units, 1025 nearly-all-resident blocks.
// __launch_bounds__(256,4) pins VGPR<=128 -> 16 waves/CU.

namespace {

typedef float f4 __attribute__((ext_vector_type(4)));

constexpr float SQ3_2 = 0.86602540378443864676f;  // sqrt(3)/2
constexpr float S6    = 0.61237243569579452455f;  // sqrt(6)/4
constexpr float S10   = 0.79056941504209483300f;  // sqrt(10)/4
constexpr float S15   = 0.96824583655185422129f;  // sqrt(15)/4

// J_l: real-SH matrix of the y<->z axis swap (Condon-Shortley phase, rows/cols
// ordered m = -l..l). J = J^T = J^-1.
template<int L> struct JM;
template<> struct JM<1> {
  static constexpr float v[3][3] = {
    { 0.f, -1.f, 0.f},
    {-1.f,  0.f, 0.f},
    { 0.f,  0.f, 1.f}};
};
template<> struct JM<2> {
  static constexpr float v[5][5] = {
    { 0.f, 0.f,  0.f,   -1.f,  0.f},
    { 0.f, 1.f,  0.f,    0.f,  0.f},
    { 0.f, 0.f, -0.5f,   0.f, -SQ3_2},
    {-1.f, 0.f,  0.f,    0.f,  0.f},
    { 0.f, 0.f, -SQ3_2,  0.f,  0.5f}};
};
template<> struct JM<3> {
  static constexpr float v[7][7] = {
    { 0.f, 0.f, 0.f, S10,  0.f,   -S6,  0.f},
    { 0.f, 1.f, 0.f, 0.f,  0.f,    0.f, 0.f},
    { 0.f, 0.f, 0.f, S6,   0.f,    S10, 0.f},
    { S10, 0.f, S6,  0.f,  0.f,    0.f, 0.f},
    { 0.f, 0.f, 0.f, 0.f, -0.25f,  0.f, -S15},
    {-S6,  0.f, S10, 0.f,  0.f,    0.f, 0.f},
    { 0.f, 0.f, 0.f, 0.f, -S15,    0.f, 0.25f}};
};

// Column q of M_l = Zalpha * J * Zbeta * J * Zgamma (column-local in q: Z only
// mixes m <-> -m within a column, J*col is one sparse mat-vec).
template<int L>
__device__ inline void compute_M_col(int q, float al, float be, float ga, float* M) {
  constexpr int D = 2 * L + 1;
  const int mq = q - L;
  float sg, cg;
  sincosf((float)mq * ga, &sg, &cg);
  float v[D];
#pragma unroll
  for (int p = 0; p < D; ++p)
    v[p] = cg * JM<L>::v[p][q] + sg * JM<L>::v[p][(D - 1) - q];
  float c1, s1;
  sincosf(be, &s1, &c1);
  float cb[L + 1], sb[L + 1];
  cb[0] = 1.f; sb[0] = 0.f;
  cb[1] = c1;  sb[1] = s1;
#pragma unroll
  for (int k = 2; k <= L; ++k) {
    cb[k] = 2.f * c1 * cb[k - 1] - cb[k - 2];
    sb[k] = 2.f * c1 * sb[k - 1] - sb[k - 2];
  }
  float w[D];
#pragma unroll
  for (int p = 0; p < D; ++p) {
    const int mp = p - L;
    const int am = mp < 0 ? -mp : mp;
    const float c = cb[am];
    const float s = mp < 0 ? -sb[am] : sb[am];
    w[p] = c * v[p] - s * v[(D - 1) - p];
  }
  float u[D];
#pragma unroll
  for (int p = 0; p < D; ++p) {
    float acc = 0.f;
#pragma unroll
    for (int r = 0; r < D; ++r) acc = fmaf(JM<L>::v[p][r], w[r], acc);
    u[p] = acc;
  }
  sincosf(al, &s1, &c1);
  float ca[L + 1], sa[L + 1];
  ca[0] = 1.f; sa[0] = 0.f;
  ca[1] = c1;  sa[1] = s1;
#pragma unroll
  for (int k = 2; k <= L; ++k) {
    ca[k] = 2.f * c1 * ca[k - 1] - ca[k - 2];
    sa[k] = 2.f * c1 * sa[k - 1] - sa[k - 2];
  }
#pragma unroll
  for (int p = 0; p < D; ++p) {
    const int mp = p - L;
    const int am = mp < 0 ? -mp : mp;
    const float c = ca[am];
    const float s = mp < 0 ? -sa[am] : sa[am];
    M[p * D + q] = c * u[p] - s * u[(D - 1) - p];
  }
}

// LDS broadcast read -> SGPR (block-uniform value; v_fma takes one SGPR src).
__device__ inline float uflds(const float* __restrict__ p) {
  return __int_as_float(__builtin_amdgcn_readfirstlane(__float_as_int(*p)));
}

// Group g (of 32) owns NC consecutive copies of dim D. Data-load burst FIRST,
// then M LDS->SGPR pulls (hidden under HBM latency), FMAs, store burst.
template<int D, int NC>
__device__ inline void run_unit(const f4* __restrict__ inU,
                                f4* __restrict__ outU,
                                const float* __restrict__ Mlds,  // LDS, D*D
                                int g, int ch) {
  const int base = g * (NC * D * 8) + ch;
  f4 v[NC][D];
#pragma unroll
  for (int j = 0; j < NC; ++j)
#pragma unroll
    for (int q = 0; q < D; ++q)
      v[j][q] = __builtin_nontemporal_load(inU + base + (j * D + q) * 8);
  float Ms[D * D];
#pragma unroll
  for (int i = 0; i < D * D; ++i) Ms[i] = uflds(Mlds + i);
  f4 o[NC][D];
#pragma unroll
  for (int j = 0; j < NC; ++j)
#pragma unroll
    for (int p = 0; p < D; ++p) {
      f4 a = Ms[p * D] * v[j][0];
#pragma unroll
      for (int q = 1; q < D; ++q) a += Ms[p * D + q] * v[j][q];
      o[j][p] = a;
    }
#pragma unroll
  for (int j = 0; j < NC; ++j)
#pragma unroll
    for (int p = 0; p < D; ++p)
      __builtin_nontemporal_store(o[j][p], outU + base + (j * D + p) * 8);
}

// Unit table per n (f4 offsets, 16896 f4 per row), 6 units/n, address-ordered:
//  k=0: l0 copy @0 (2048 f4)          k=1,2: l1 128 copies @2048+3072(k-1)
//  k=3,4: l2 64 copies @8192+2560(k-3) k=5: l3 64 copies @13312 (3584 f4)
// Grid stride 1025 (= 5 mod 6): each block cycles all unit types (balanced),
// unit order == memory order (sliding contiguous window).
__global__ __launch_bounds__(256, 4) void wigner_kernel(
    const float* __restrict__ in, const float* __restrict__ alpha,
    const float* __restrict__ beta, const float* __restrict__ gamma,
    float* __restrict__ out, int n_units, int grid) {
  __shared__ float Mlds[49];
  const int t = threadIdx.x;
  const int g = t >> 3, ch = t & 7;
  for (int u = blockIdx.x; u < n_units; u += grid) {
    const int n = u / 6, k = u - n * 6;
    const size_t base = (size_t)n * 16896;
    const f4* inN = (const f4*)in + base;
    f4* outN = (f4*)out + base;
    if (k == 0) {
      f4 c[8];
#pragma unroll
      for (int j = 0; j < 8; ++j)
        c[j] = __builtin_nontemporal_load(inN + t + 256 * j);
#pragma unroll
      for (int j = 0; j < 8; ++j)
        __builtin_nontemporal_store(c[j], outN + t + 256 * j);
    } else {
      __syncthreads();  // prior unit's M readers are done before overwrite
      if (k <= 2) {
        if (t < 3) compute_M_col<1>(t, alpha[n], beta[n], gamma[n], Mlds);
      } else if (k <= 4) {
        if (t < 5) compute_M_col<2>(t, alpha[n], beta[n], gamma[n], Mlds);
      } else {
        if (t < 7) compute_M_col<3>(t, alpha[n], beta[n], gamma[n], Mlds);
      }
      __syncthreads();  // M published
      if (k <= 2) {
        const int soff = 2048 + (k - 1) * 3072;
        run_unit<3, 4>(inN + soff, outN + soff, Mlds, g, ch);
      } else if (k <= 4) {
        const int soff = 8192 + (k - 3) * 2560;
        run_unit<5, 2>(inN + soff, outN + soff, Mlds, g, ch);
      } else {
        run_unit<7, 2>(inN + 13312, outN + 13312, Mlds, g, ch);
      }
    }
  }
}

}  // namespace

extern "C" void kernel_launch(void* const* d_in, const int* in_sizes, int n_in,
                              void* d_out, int out_size, void* d_ws, size_t ws_size,
                              hipStream_t stream) {
  const float* in    = (const float*)d_in[0];
  const float* alpha = (const float*)d_in[1];
  const float* beta  = (const float*)d_in[2];
  const float* gamma = (const float*)d_in[3];
  float* out = (float*)d_out;
  const int n_batch = in_sizes[1];  // 1024

  const int n_units = n_batch * 6;
  const int grid = n_units < 1025 ? n_units : 1025;  // ~all-resident, 5 mod 6
  wigner_kernel<<<grid, 256, 0, stream>>>(in, alpha, beta, gamma, out,
                                          n_units, grid);
}

// Round 8
// 101.998 us; speedup vs baseline: 1.3380x; 1.0164x over previous
//
#include <hip/hip_runtime.h>
#include <math.h>

// WignerDRotation: out = Z(alpha) * J * Z(beta) * J * Z(gamma) * x, block-diagonal
// over irreps [0]*256 + [1]*256 + [2]*128 + [3]*64, DIM=2112, CH=32, N=1024.
// All copies of the same l share one d x d composite matrix M_l per batch row.
//
// Round-8 structure: round 7 (single fused kernel, burst issue, SGPR-M FMAs,
// sliding-window grid-stride over 6144 memory-ordered units) with the per-unit
// sync cost halved: ONE raw s_barrier per non-copy unit (lgkmcnt-only drain,
// loads/stores stay in flight across it, vs __syncthreads' vmcnt(0) drain x2),
// M double-buffered in LDS so the single barrier is race-free, and the M
// sincos chain issued AFTER the data-load burst so it hides under HBM latency.

namespace {

typedef float f4 __attribute__((ext_vector_type(4)));

constexpr float SQ3_2 = 0.86602540378443864676f;  // sqrt(3)/2
constexpr float S6    = 0.61237243569579452455f;  // sqrt(6)/4
constexpr float S10   = 0.79056941504209483300f;  // sqrt(10)/4
constexpr float S15   = 0.96824583655185422129f;  // sqrt(15)/4

// J_l: real-SH matrix of the y<->z axis swap (Condon-Shortley phase, rows/cols
// ordered m = -l..l). J = J^T = J^-1.
template<int L> struct JM;
template<> struct JM<1> {
  static constexpr float v[3][3] = {
    { 0.f, -1.f, 0.f},
    {-1.f,  0.f, 0.f},
    { 0.f,  0.f, 1.f}};
};
template<> struct JM<2> {
  static constexpr float v[5][5] = {
    { 0.f, 0.f,  0.f,   -1.f,  0.f},
    { 0.f, 1.f,  0.f,    0.f,  0.f},
    { 0.f, 0.f, -0.5f,   0.f, -SQ3_2},
    {-1.f, 0.f,  0.f,    0.f,  0.f},
    { 0.f, 0.f, -SQ3_2,  0.f,  0.5f}};
};
template<> struct JM<3> {
  static constexpr float v[7][7] = {
    { 0.f, 0.f, 0.f, S10,  0.f,   -S6,  0.f},
    { 0.f, 1.f, 0.f, 0.f,  0.f,    0.f, 0.f},
    { 0.f, 0.f, 0.f, S6,   0.f,    S10, 0.f},
    { S10, 0.f, S6,  0.f,  0.f,    0.f, 0.f},
    { 0.f, 0.f, 0.f, 0.f, -0.25f,  0.f, -S15},
    {-S6,  0.f, S10, 0.f,  0.f,    0.f, 0.f},
    { 0.f, 0.f, 0.f, 0.f, -S15,    0.f, 0.25f}};
};

// Column q of M_l = Zalpha * J * Zbeta * J * Zgamma (column-local in q: Z only
// mixes m <-> -m within a column, J*col is one sparse mat-vec).
template<int L>
__device__ inline void compute_M_col(int q, float al, float be, float ga, float* M) {
  constexpr int D = 2 * L + 1;
  const int mq = q - L;
  float sg, cg;
  __sincosf((float)mq * ga, &sg, &cg);
  float v[D];
#pragma unroll
  for (int p = 0; p < D; ++p)
    v[p] = cg * JM<L>::v[p][q] + sg * JM<L>::v[p][(D - 1) - q];
  float c1, s1;
  __sincosf(be, &s1, &c1);
  float cb[L + 1], sb[L + 1];
  cb[0] = 1.f; sb[0] = 0.f;
  cb[1] = c1;  sb[1] = s1;
#pragma unroll
  for (int k = 2; k <= L; ++k) {
    cb[k] = 2.f * c1 * cb[k - 1] - cb[k - 2];
    sb[k] = 2.f * c1 * sb[k - 1] - sb[k - 2];
  }
  float w[D];
#pragma unroll
  for (int p = 0; p < D; ++p) {
    const int mp = p - L;
    const int am = mp < 0 ? -mp : mp;
    const float c = cb[am];
    const float s = mp < 0 ? -sb[am] : sb[am];
    w[p] = c * v[p] - s * v[(D - 1) - p];
  }
  float u[D];
#pragma unroll
  for (int p = 0; p < D; ++p) {
    float acc = 0.f;
#pragma unroll
    for (int r = 0; r < D; ++r) acc = fmaf(JM<L>::v[p][r], w[r], acc);
    u[p] = acc;
  }
  __sincosf(al, &s1, &c1);
  float ca[L + 1], sa[L + 1];
  ca[0] = 1.f; sa[0] = 0.f;
  ca[1] = c1;  sa[1] = s1;
#pragma unroll
  for (int k = 2; k <= L; ++k) {
    ca[k] = 2.f * c1 * ca[k - 1] - ca[k - 2];
    sa[k] = 2.f * c1 * sa[k - 1] - sa[k - 2];
  }
#pragma unroll
  for (int p = 0; p < D; ++p) {
    const int mp = p - L;
    const int am = mp < 0 ? -mp : mp;
    const float c = ca[am];
    const float s = mp < 0 ? -sa[am] : sa[am];
    M[p * D + q] = c * u[p] - s * u[(D - 1) - p];
  }
}

// LDS broadcast read -> SGPR (block-uniform value; v_fma takes one SGPR src).
__device__ inline float uflds(const float* __restrict__ p) {
  return __int_as_float(__builtin_amdgcn_readfirstlane(__float_as_int(*p)));
}

// Publish LDS writes and rendezvous WITHOUT draining vmcnt: outstanding global
// loads/stores stay in flight across the barrier (unlike __syncthreads).
__device__ inline void lds_barrier() {
  asm volatile("s_waitcnt lgkmcnt(0)" ::: "memory");
  __builtin_amdgcn_s_barrier();
  __builtin_amdgcn_sched_barrier(0);  // pin following ds_reads after the barrier
}

// Non-copy unit: group g (of 32) owns NC consecutive copies of dim D.
// Pipeline: load burst -> (M sincos chain in <=D lanes, hidden under HBM
// latency) -> lds_barrier -> M->SGPR -> FMA -> store burst.
template<int L, int NC>
__device__ inline void run_unit(const f4* __restrict__ inU,
                                f4* __restrict__ outU,
                                float al, float be, float ga, bool mlane,
                                float* __restrict__ Mlds,  // LDS, D*D (cur buf)
                                int g, int ch, int t) {
  constexpr int D = 2 * L + 1;
  const int base = g * (NC * D * 8) + ch;
  f4 v[NC][D];
#pragma unroll
  for (int j = 0; j < NC; ++j)
#pragma unroll
    for (int q = 0; q < D; ++q)
      v[j][q] = __builtin_nontemporal_load(inU + base + (j * D + q) * 8);
  if (mlane) compute_M_col<L>(t, al, be, ga, Mlds);
  lds_barrier();
  float Ms[D * D];
#pragma unroll
  for (int i = 0; i < D * D; ++i) Ms[i] = uflds(Mlds + i);
  f4 o[NC][D];
#pragma unroll
  for (int j = 0; j < NC; ++j)
#pragma unroll
    for (int p = 0; p < D; ++p) {
      f4 a = Ms[p * D] * v[j][0];
#pragma unroll
      for (int q = 1; q < D; ++q) a += Ms[p * D + q] * v[j][q];
      o[j][p] = a;
    }
#pragma unroll
  for (int j = 0; j < NC; ++j)
#pragma unroll
    for (int p = 0; p < D; ++p)
      __builtin_nontemporal_store(o[j][p], outU + base + (j * D + p) * 8);
}

// Unit table per n (f4 offsets, 16896 f4 per row), 6 units/n, address-ordered:
//  k=0: l0 copy @0 (2048 f4)           k=1,2: l1 128 copies @2048+3072(k-1)
//  k=3,4: l2 64 copies @8192+2560(k-3) k=5: l3 64 copies @13312 (3584 f4)
// Grid stride 1025 (= 5 mod 6): each block cycles all unit types (balanced:
// one of each k per 6 units = exactly 264 KB), unit order == memory order
// (sliding contiguous window). Double-buffered M -> one barrier per unit is
// race-free: buf A's readers run in the epoch before buf A's next writers.
__global__ __launch_bounds__(256, 4) void wigner_kernel(
    const float* __restrict__ in, const float* __restrict__ alpha,
    const float* __restrict__ beta, const float* __restrict__ gamma,
    float* __restrict__ out, int n_units, int grid) {
  __shared__ float Mlds[2][49];
  const int t = threadIdx.x;
  const int g = t >> 3, ch = t & 7;
  int cur = 0;
  for (int u = blockIdx.x; u < n_units; u += grid) {
    const int n = u / 6, k = u - n * 6;
    const size_t base = (size_t)n * 16896;
    const f4* inN = (const f4*)in + base;
    f4* outN = (f4*)out + base;
    if (k == 0) {
      f4 c[8];
#pragma unroll
      for (int j = 0; j < 8; ++j)
        c[j] = __builtin_nontemporal_load(inN + t + 256 * j);
#pragma unroll
      for (int j = 0; j < 8; ++j)
        __builtin_nontemporal_store(c[j], outN + t + 256 * j);
    } else {
      const float al = alpha[n], be = beta[n], ga = gamma[n];
      float* Mb = Mlds[cur];
      if (k <= 2) {
        const int soff = 2048 + (k - 1) * 3072;
        run_unit<1, 4>(inN + soff, outN + soff, al, be, ga, t < 3, Mb, g, ch, t);
      } else if (k <= 4) {
        const int soff = 8192 + (k - 3) * 2560;
        run_unit<2, 2>(inN + soff, outN + soff, al, be, ga, t < 5, Mb, g, ch, t);
      } else {
        run_unit<3, 2>(inN + 13312, outN + 13312, al, be, ga, t < 7, Mb, g, ch, t);
      }
      cur ^= 1;
    }
  }
}

}  // namespace

extern "C" void kernel_launch(void* const* d_in, const int* in_sizes, int n_in,
                              void* d_out, int out_size, void* d_ws, size_t ws_size,
                              hipStream_t stream) {
  const float* in    = (const float*)d_in[0];
  const float* alpha = (const float*)d_in[1];
  const float* beta  = (const float*)d_in[2];
  const float* gamma = (const float*)d_in[3];
  float* out = (float*)d_out;
  const int n_batch = in_sizes[1];  // 1024

  const int n_units = n_batch * 6;
  const int grid = n_units < 1025 ? n_units : 1025;  // ~all-resident, 5 mod 6
  wigner_kernel<<<grid, 256, 0, stream>>>(in, alpha, beta, gamma, out,
                                          n_units, grid);
}